// Round 9
// baseline (150.013 us; speedup 1.0000x reference)
//
#include <hip/hip_runtime.h>
#include <hip/hip_bf16.h>

typedef __bf16 bf16;
typedef __bf16 bf16x4 __attribute__((ext_vector_type(4)));
typedef __bf16 bf16x8 __attribute__((ext_vector_type(8)));
typedef float f32x4 __attribute__((ext_vector_type(4)));

#define MFMA_16x16x32(A, B, C) __builtin_amdgcn_mfma_f32_16x16x32_bf16(A, B, C, 0, 0, 0)

static_assert(sizeof(bf16x8) == 16, "bf16x8 must be 16B");

__device__ __forceinline__ bf16x8 cast8(float4 lo, float4 hi) {
  return (bf16x8){(bf16)lo.x, (bf16)lo.y, (bf16)lo.z, (bf16)lo.w,
                  (bf16)hi.x, (bf16)hi.y, (bf16)hi.z, (bf16)hi.w};
}

// ---------------------------------------------------------------------------
// Kernel 0: cast + transpose weights: Wt[p][h][c] = W_p[c][h].
// ---------------------------------------------------------------------------
__global__ __launch_bounds__(256) void wtrans_kernel(
    const float* __restrict__ Wq, const float* __restrict__ Wk,
    const float* __restrict__ Wv, bf16* __restrict__ Wt)
{
  int idx = blockIdx.x * 256 + threadIdx.x;   // 3*64*1024
  int p = idx >> 16;
  int rem = idx & 65535;
  int h = rem >> 10;
  int c = rem & 1023;
  const float* W = (p == 0) ? Wq : (p == 1) ? Wk : Wv;
  Wt[idx] = (bf16)W[c * 64 + h];
}

// ---------------------------------------------------------------------------
// Kernel 1: projections — barrier-free main loop + block-resident B.
// 256 blocks x 512 thr (8 waves), 1 block/CU (128 KB dynamic LDS).
// Families: bid<86 -> Q=q@Wq ; <171 -> K=k@Wk ; else V=k@Wv (transposed out).
// Each block stages its FULL weight matrix (64x1024 bf16 = 128 KB) into LDS
// once (XOR-swizzled 16B-chunk index: phys = ch ^ (row&7) -> ds_read 2-way
// max, which is free), then ONE __syncthreads. Main loop: each wave
// independently grid-strides over 16-row strips of A; per 32-k chunk:
// 2 float4 A-loads (4-named-set rotation, ~4 chunks = 32KB/wave in flight,
// compiler inserts counted vmcnt at consume) + 4 swizzled ds_read_b128 +
// 4 MFMA. ZERO barriers, zero cross-wave sync in the loop — the regime R1
// proved runs at the ~6.3 TB/s delivery ceiling — at minimal traffic
// (A 384 MB + B 32 MB one-time).
// ---------------------------------------------------------------------------
__global__ __launch_bounds__(512) void proj_kernel(
    const float* __restrict__ qin, const float* __restrict__ kin,
    const bf16* __restrict__ Wt,
    bf16* __restrict__ Qb, bf16* __restrict__ Kb, bf16* __restrict__ Vtb)
{
  extern __shared__ __align__(16) bf16 Bsh[];   // [64][1024], chunk-swizzled

  const int bid = blockIdx.x;     // 0..255
  int fam, fbid, fnb;
  if (bid < 86)       { fam = 0; fbid = bid;       fnb = 86; }
  else if (bid < 171) { fam = 1; fbid = bid - 86;  fnb = 85; }
  else                { fam = 2; fbid = bid - 171; fnb = 85; }
  const float* A = (fam == 0) ? qin : kin;
  const bf16* W = Wt + (size_t)fam * 65536;

  const int tid = threadIdx.x;    // 0..511
  const int lane = tid & 63;
  const int w = tid >> 6;         // wave 0..7
  const int g = lane >> 4;
  const int r = lane & 15;

  // --- stage B once: coalesced global read, swizzled LDS chunk write ---
  #pragma unroll
  for (int i = 0; i < 16; ++i) {
    int cid = i * 512 + tid;              // 16B-chunk id, 0..8191
    int row = cid >> 7, ch = cid & 127;
    int pch = ch ^ (row & 7);             // swizzle
    *(bf16x8*)&Bsh[row * 1024 + pch * 8] =
        *(const bf16x8*)(W + (size_t)row * 1024 + ch * 8);
  }
  __syncthreads();                        // the ONLY barrier

  // --- free-running strip loop: strip = 16 rows, 2048 strips/family ---
  for (int s = fbid * 8 + w; s < 2048; s += fnb * 8) {
    const float* ap = A + ((size_t)s * 16 + r) * 1024 + g * 8;

    f32x4 acc[4];
    #pragma unroll
    for (int cf = 0; cf < 4; cf++) acc[cf] = (f32x4){0.f, 0.f, 0.f, 0.f};

    // 4 named prefetch sets (static indexing), depth ~3-4 chunks
    float4 Pa0, Pb0, Pa1, Pb1, Pa2, Pb2, Pa3, Pb3;

#define ISS(S, C)                                                        \
  do {                                                                   \
    Pa##S = *(const float4*)(ap + (C) * 32);                             \
    Pb##S = *(const float4*)(ap + (C) * 32 + 4);                         \
  } while (0)

#define CSTEP(S, C)                                                     \
  do {                                                                   \
    bf16x8 af = cast8(Pa##S, Pb##S);                                     \
    _Pragma("unroll")                                                    \
    for (int cf = 0; cf < 4; cf++) {                                     \
      int rw = cf * 16 + r;                                              \
      int pch = (((C) << 2) + g) ^ (rw & 7);                             \
      bf16x8 bfrag = *(const bf16x8*)&Bsh[rw * 1024 + pch * 8];          \
      acc[cf] = MFMA_16x16x32(af, bfrag, acc[cf]);                       \
    }                                                                    \
  } while (0)

    ISS(0, 0); ISS(1, 1); ISS(2, 2);
    #pragma unroll 1
    for (int j = 0; j < 8; ++j) {
      const int c0 = 4 * j;
      if (j < 8 - 1) {
        CSTEP(0, c0 + 0); ISS(3, c0 + 3);
        CSTEP(1, c0 + 1); ISS(0, c0 + 4);
        CSTEP(2, c0 + 2); ISS(1, c0 + 5);
        CSTEP(3, c0 + 3); ISS(2, c0 + 6);
      } else {
        CSTEP(0, c0 + 0); ISS(3, c0 + 3);
        CSTEP(1, c0 + 1);
        CSTEP(2, c0 + 2);
        CSTEP(3, c0 + 3);
      }
    }
#undef ISS
#undef CSTEP

    // --- epilogue: C/D layout row=(l>>4)*4+j, col=l&15 ---
    if (fam < 2) {
      bf16* O = (fam == 0) ? Qb : Kb;
      #pragma unroll
      for (int cf = 0; cf < 4; cf++) {
        #pragma unroll
        for (int jj = 0; jj < 4; jj++) {
          int rg = s * 16 + g * 4 + jj;
          O[(size_t)rg * 64 + cf * 16 + r] = (bf16)acc[cf][jj];
        }
      }
    } else {
      // V: transposed store, 4 consecutive-t bf16 packed into one 8B write
      int bb = (s * 16) >> 11;
      int t0 = (s * 16 + g * 4) & 2047;
      #pragma unroll
      for (int cf = 0; cf < 4; cf++) {
        bf16x4 v = (bf16x4){(bf16)acc[cf][0], (bf16)acc[cf][1],
                            (bf16)acc[cf][2], (bf16)acc[cf][3]};
        *(bf16x4*)&Vtb[((size_t)(bb * 64 + cf * 16 + r)) * 2048 + t0] = v;
      }
    }
  }
}

// ---------------------------------------------------------------------------
// Kernel 2: causal flash attention (unchanged).
// ---------------------------------------------------------------------------
__global__ __launch_bounds__(256) void attn_kernel(
    const bf16* __restrict__ Qb, const bf16* __restrict__ Kb,
    const bf16* __restrict__ Vtb, float* __restrict__ out)
{
  const int qt = (int)(gridDim.x - 1 - blockIdx.x);   // heavy blocks first
  const int b = blockIdx.y;
  const int tid = threadIdx.x;
  const int lane = tid & 63;
  const int w = tid >> 6;
  const int g = lane >> 4;
  const int r = lane & 15;

  __shared__ __align__(16) bf16 Ks[64][80];
  __shared__ __align__(16) bf16 Vs[64][80];
  __shared__ __align__(16) bf16 Ps[4][16][80];

  const int q0 = qt * 64 + w * 16;
  const bf16* qp = Qb + (size_t)(b * 2048 + q0 + r) * 64 + g * 8;
  const bf16x8 qf0 = *(const bf16x8*)qp;
  const bf16x8 qf1 = *(const bf16x8*)(qp + 32);

  f32x4 acc_o[4];
  #pragma unroll
  for (int hf = 0; hf < 4; hf++) acc_o[hf] = (f32x4){0.f, 0.f, 0.f, 0.f};
  float m_r[4] = {-1e30f, -1e30f, -1e30f, -1e30f};
  float l_r[4] = {0.f, 0.f, 0.f, 0.f};
  const float scale = 0.03125f;   // 1/sqrt(1024)

  const int sh = tid >> 2;
  const int sc = (tid & 3) * 16;

  for (int kv = 0; kv <= qt; kv++) {
    {
      const bf16* kp = Kb + (size_t)(b * 2048 + kv * 64 + sh) * 64 + sc;
      *(bf16x8*)&Ks[sh][sc]     = *(const bf16x8*)kp;
      *(bf16x8*)&Ks[sh][sc + 8] = *(const bf16x8*)(kp + 8);
      const bf16* vp = Vtb + (size_t)(b * 64 + sh) * 2048 + kv * 64 + sc;
      *(bf16x8*)&Vs[sh][sc]     = *(const bf16x8*)vp;
      *(bf16x8*)&Vs[sh][sc + 8] = *(const bf16x8*)(vp + 8);
    }
    __syncthreads();

    f32x4 s[4];
    #pragma unroll
    for (int cf = 0; cf < 4; cf++) {
      bf16x8 kf0 = *(const bf16x8*)&Ks[cf * 16 + r][g * 8];
      bf16x8 kf1 = *(const bf16x8*)&Ks[cf * 16 + r][32 + g * 8];
      f32x4 t = (f32x4){0.f, 0.f, 0.f, 0.f};
      t = MFMA_16x16x32(qf0, kf0, t);
      t = MFMA_16x16x32(qf1, kf1, t);
      s[cf] = t;
    }

    const bool diag = (kv == qt);
    float pm[4] = {-1e30f, -1e30f, -1e30f, -1e30f};
    #pragma unroll
    for (int cf = 0; cf < 4; cf++) {
      #pragma unroll
      for (int j = 0; j < 4; j++) {
        float v = s[cf][j] * scale;
        if (diag && (cf * 16 + r) > (w * 16 + g * 4 + j)) v = -1e30f;
        s[cf][j] = v;
        pm[j] = fmaxf(pm[j], v);
      }
    }
    #pragma unroll
    for (int j = 0; j < 4; j++) {
      #pragma unroll
      for (int msk = 1; msk < 16; msk <<= 1)
        pm[j] = fmaxf(pm[j], __shfl_xor(pm[j], msk, 64));
    }
    float corr[4];
    #pragma unroll
    for (int j = 0; j < 4; j++) {
      float mn = fmaxf(m_r[j], pm[j]);
      corr[j] = __expf(m_r[j] - mn);
      m_r[j] = mn;
    }
    float rs[4] = {0.f, 0.f, 0.f, 0.f};
    #pragma unroll
    for (int cf = 0; cf < 4; cf++) {
      #pragma unroll
      for (int j = 0; j < 4; j++) {
        float pv = __expf(s[cf][j] - m_r[j]);
        s[cf][j] = pv;
        rs[j] += pv;
      }
    }
    #pragma unroll
    for (int j = 0; j < 4; j++) {
      #pragma unroll
      for (int msk = 1; msk < 16; msk <<= 1)
        rs[j] += __shfl_xor(rs[j], msk, 64);
      l_r[j] = l_r[j] * corr[j] + rs[j];
    }
    #pragma unroll
    for (int hf = 0; hf < 4; hf++)
      #pragma unroll
      for (int j = 0; j < 4; j++)
        acc_o[hf][j] *= corr[j];

    #pragma unroll
    for (int cf = 0; cf < 4; cf++)
      #pragma unroll
      for (int j = 0; j < 4; j++)
        Ps[w][g * 4 + j][cf * 16 + r] = (bf16)s[cf][j];

    __syncthreads();

    #pragma unroll
    for (int ss = 0; ss < 2; ss++) {
      bf16x8 pf = *(const bf16x8*)&Ps[w][r][ss * 32 + g * 8];
      #pragma unroll
      for (int hf = 0; hf < 4; hf++) {
        bf16x8 vf = *(const bf16x8*)&Vs[hf * 16 + r][ss * 32 + g * 8];
        acc_o[hf] = MFMA_16x16x32(pf, vf, acc_o[hf]);
      }
    }
    __syncthreads();
  }

  float inv[4];
  #pragma unroll
  for (int j = 0; j < 4; j++) inv[j] = 1.0f / l_r[j];
  const size_t ob = (size_t)(b * 2048 + q0) * 64;
  #pragma unroll
  for (int hf = 0; hf < 4; hf++)
    #pragma unroll
    for (int j = 0; j < 4; j++)
      out[ob + (size_t)(g * 4 + j) * 64 + hf * 16 + r] = acc_o[hf][j] * inv[j];
}

// ---------------------------------------------------------------------------
extern "C" void kernel_launch(void* const* d_in, const int* in_sizes, int n_in,
                              void* d_out, int out_size, void* d_ws, size_t ws_size,
                              hipStream_t stream)
{
  const float* q  = (const float*)d_in[0];
  const float* k  = (const float*)d_in[1];
  const float* Wq = (const float*)d_in[2];
  const float* Wk = (const float*)d_in[3];
  const float* Wv = (const float*)d_in[4];
  float* out = (float*)d_out;

  char* ws = (char*)d_ws;
  bf16* Qb  = (bf16*)(ws);                      // [16*2048][64] bf16, 4MB
  bf16* Kb  = (bf16*)(ws + (4u << 20));         // [16*2048][64] bf16, 4MB
  bf16* Vtb = (bf16*)(ws + (8u << 20));         // [16][64][2048] bf16, 4MB
  bf16* Wt  = (bf16*)(ws + (12u << 20));        // [3][64][1024] bf16, 384KB

  hipLaunchKernelGGL(wtrans_kernel, dim3(768), dim3(256), 0, stream,
                     Wq, Wk, Wv, Wt);
  hipLaunchKernelGGL(proj_kernel, dim3(256), dim3(512),
                     64 * 1024 * sizeof(bf16) /* 128 KB dynamic LDS */,
                     stream, q, k, Wt, Qb, Kb, Vtb);
  hipLaunchKernelGGL(attn_kernel, dim3(32, 16), dim3(256), 0, stream,
                     Qb, Kb, Vtb, out);
}

// Round 10
// 146.905 us; speedup vs baseline: 1.0212x; 1.0212x over previous
//
#include <hip/hip_runtime.h>
#include <hip/hip_bf16.h>

typedef __bf16 bf16;
typedef __bf16 bf16x4 __attribute__((ext_vector_type(4)));
typedef __bf16 bf16x8 __attribute__((ext_vector_type(8)));
typedef float f32x4 __attribute__((ext_vector_type(4)));

#define MFMA_16x16x32(A, B, C) __builtin_amdgcn_mfma_f32_16x16x32_bf16(A, B, C, 0, 0, 0)

static_assert(sizeof(bf16x8) == 16, "bf16x8 must be 16B");

__device__ __forceinline__ bf16x8 cast8(float4 lo, float4 hi) {
  return (bf16x8){(bf16)lo.x, (bf16)lo.y, (bf16)lo.z, (bf16)lo.w,
                  (bf16)hi.x, (bf16)hi.y, (bf16)hi.z, (bf16)hi.w};
}

// ---------------------------------------------------------------------------
// Kernel 0: cast + transpose weights: Wt[p][h][c] = W_p[c][h].
// ---------------------------------------------------------------------------
__global__ __launch_bounds__(256) void wtrans_kernel(
    const float* __restrict__ Wq, const float* __restrict__ Wk,
    const float* __restrict__ Wv, bf16* __restrict__ Wt)
{
  int idx = blockIdx.x * 256 + threadIdx.x;   // 3*64*1024
  int p = idx >> 16;
  int rem = idx & 65535;
  int h = rem >> 10;
  int c = rem & 1023;
  const float* W = (p == 0) ? Wq : (p == 1) ? Wk : Wv;
  Wt[idx] = (bf16)W[c * 64 + h];
}

// ---------------------------------------------------------------------------
// Kernel 1: projections — line-efficient, barrier-free.
// Model (fits R1..R9): the wall is ~41-45 cache-LINE requests/cycle chip-wide.
// MFMA-fragment-layout A loads (16B @ 32B stride) touch every line TWICE ->
// 2x line cost. Fix: load A lane-CONTIGUOUS (4 lanes x 16B = full 64B line
// per row, 1 touch/line — m13's 6.3TB/s pattern), then redistribute to
// fragment layout through a PER-WAVE private LDS strip: same-wave
// ds_write -> ds_read is ordered by lgkmcnt, so NO barrier — the loop stays
// free-running (R1/R9 regime). B stays block-resident in LDS (one-time
// 32MB). __launch_bounds__(512,2) caps assumed occupancy at 8 waves/CU
// (the LDS-imposed truth) so regalloc keeps the 4-deep A prefetch
// (R6/R9's collapse: compiler targeted 16 waves -> VGPR 68-80).
// LDS: 128KB B + 8 waves x 2KB stage = 144KB. 256 blocks = 1/CU.
// ---------------------------------------------------------------------------
__global__ __launch_bounds__(512, 2) void proj_kernel(
    const float* __restrict__ qin, const float* __restrict__ kin,
    const bf16* __restrict__ Wt,
    bf16* __restrict__ Qb, bf16* __restrict__ Kb, bf16* __restrict__ Vtb)
{
  extern __shared__ __align__(16) bf16 Bsh[];          // [64][1024] swizzled
  float* stage = (float*)(Bsh + 65536);                // 8 x [16][32] f32

  const int bid = blockIdx.x;     // 0..255
  int fam, fbid, fnb;
  if (bid < 86)       { fam = 0; fbid = bid;       fnb = 86; }
  else if (bid < 171) { fam = 1; fbid = bid - 86;  fnb = 85; }
  else                { fam = 2; fbid = bid - 171; fnb = 85; }
  const float* A = (fam == 0) ? qin : kin;
  const bf16* W = Wt + (size_t)fam * 65536;

  const int tid = threadIdx.x;    // 0..511
  const int lane = tid & 63;
  const int w = tid >> 6;         // wave 0..7
  const int g = lane >> 4;
  const int r = lane & 15;
  const int rl = lane >> 2;       // contiguous-load row 0..15
  const int l4 = lane & 3;        // contiguous-load 16B slot within 64B

  // --- stage B once: coalesced read, swizzled 16B-chunk write ---
  #pragma unroll
  for (int i = 0; i < 16; ++i) {
    int cid = i * 512 + tid;              // 16B-chunk id, 0..8191
    int row = cid >> 7, ch = cid & 127;
    int pch = ch ^ (row & 7);
    *(bf16x8*)&Bsh[row * 1024 + pch * 8] =
        *(const bf16x8*)(W + (size_t)row * 1024 + ch * 8);
  }
  __syncthreads();                        // the ONLY barrier

  // per-wave stage addresses (float indices), XOR-swizzled 16B slots
  float* const sw0 = &stage[w * 512 + rl * 32 + ((l4    ) ^ (rl & 7)) * 4];
  float* const sw1 = &stage[w * 512 + rl * 32 + ((l4 + 4) ^ (rl & 7)) * 4];
  const float* const sr0 = &stage[w * 512 + r * 32 + (((2 * g)    ) ^ (r & 7)) * 4];
  const float* const sr1 = &stage[w * 512 + r * 32 + (((2 * g) | 1) ^ (r & 7)) * 4];

  // --- free-running strip loop: strip = 16 rows ---
  for (int s = fbid * 8 + w; s < 2048; s += fnb * 8) {
    // lane-contiguous A pointer: full-line requests (1 touch/line)
    const float* ap = A + ((size_t)s * 16 + rl) * 1024 + l4 * 4;

    f32x4 acc[4];
    #pragma unroll
    for (int cf = 0; cf < 4; cf++) acc[cf] = (f32x4){0.f, 0.f, 0.f, 0.f};

    float4 Pa0, Pb0, Pa1, Pb1, Pa2, Pb2, Pa3, Pb3;   // 4 named sets

#define ISS(S, C)                                                        \
  do {                                                                   \
    Pa##S = *(const float4*)(ap + (C) * 32);                             \
    Pb##S = *(const float4*)(ap + (C) * 32 + 16);                        \
  } while (0)

#define STEPC(S, C)                                                      \
  do {                                                                   \
    *(float4*)sw0 = Pa##S;                                               \
    *(float4*)sw1 = Pb##S;                                               \
    float4 fA = *(const float4*)sr0;                                     \
    float4 fB = *(const float4*)sr1;                                     \
    bf16x8 af = cast8(fA, fB);                                           \
    _Pragma("unroll")                                                    \
    for (int cf = 0; cf < 4; cf++) {                                     \
      int rw = cf * 16 + r;                                              \
      int pch = (((C) << 2) + g) ^ (rw & 7);                             \
      bf16x8 bfrag = *(const bf16x8*)&Bsh[rw * 1024 + pch * 8];          \
      acc[cf] = MFMA_16x16x32(af, bfrag, acc[cf]);                       \
    }                                                                    \
  } while (0)

    ISS(0, 0); ISS(1, 1); ISS(2, 2); ISS(3, 3);
    #pragma unroll 1
    for (int jc = 0; jc < 8; ++jc) {
      const int c0 = 4 * jc;
      STEPC(0, c0 + 0); if (jc < 7) ISS(0, c0 + 4);
      STEPC(1, c0 + 1); if (jc < 7) ISS(1, c0 + 5);
      STEPC(2, c0 + 2); if (jc < 7) ISS(2, c0 + 6);
      STEPC(3, c0 + 3); if (jc < 7) ISS(3, c0 + 7);
    }
#undef ISS
#undef STEPC

    // --- epilogue: C/D layout row=(l>>4)*4+j, col=l&15 ---
    if (fam < 2) {
      bf16* O = (fam == 0) ? Qb : Kb;
      #pragma unroll
      for (int cf = 0; cf < 4; cf++) {
        #pragma unroll
        for (int jj = 0; jj < 4; jj++) {
          int rg = s * 16 + g * 4 + jj;
          O[(size_t)rg * 64 + cf * 16 + r] = (bf16)acc[cf][jj];
        }
      }
    } else {
      int bb = (s * 16) >> 11;
      int t0 = (s * 16 + g * 4) & 2047;
      #pragma unroll
      for (int cf = 0; cf < 4; cf++) {
        bf16x4 v = (bf16x4){(bf16)acc[cf][0], (bf16)acc[cf][1],
                            (bf16)acc[cf][2], (bf16)acc[cf][3]};
        *(bf16x4*)&Vtb[((size_t)(bb * 64 + cf * 16 + r)) * 2048 + t0] = v;
      }
    }
  }
}

// ---------------------------------------------------------------------------
// Kernel 2: causal flash attention (unchanged).
// ---------------------------------------------------------------------------
__global__ __launch_bounds__(256) void attn_kernel(
    const bf16* __restrict__ Qb, const bf16* __restrict__ Kb,
    const bf16* __restrict__ Vtb, float* __restrict__ out)
{
  const int qt = (int)(gridDim.x - 1 - blockIdx.x);   // heavy blocks first
  const int b = blockIdx.y;
  const int tid = threadIdx.x;
  const int lane = tid & 63;
  const int w = tid >> 6;
  const int g = lane >> 4;
  const int r = lane & 15;

  __shared__ __align__(16) bf16 Ks[64][80];
  __shared__ __align__(16) bf16 Vs[64][80];
  __shared__ __align__(16) bf16 Ps[4][16][80];

  const int q0 = qt * 64 + w * 16;
  const bf16* qp = Qb + (size_t)(b * 2048 + q0 + r) * 64 + g * 8;
  const bf16x8 qf0 = *(const bf16x8*)qp;
  const bf16x8 qf1 = *(const bf16x8*)(qp + 32);

  f32x4 acc_o[4];
  #pragma unroll
  for (int hf = 0; hf < 4; hf++) acc_o[hf] = (f32x4){0.f, 0.f, 0.f, 0.f};
  float m_r[4] = {-1e30f, -1e30f, -1e30f, -1e30f};
  float l_r[4] = {0.f, 0.f, 0.f, 0.f};
  const float scale = 0.03125f;   // 1/sqrt(1024)

  const int sh = tid >> 2;
  const int sc = (tid & 3) * 16;

  for (int kv = 0; kv <= qt; kv++) {
    {
      const bf16* kp = Kb + (size_t)(b * 2048 + kv * 64 + sh) * 64 + sc;
      *(bf16x8*)&Ks[sh][sc]     = *(const bf16x8*)kp;
      *(bf16x8*)&Ks[sh][sc + 8] = *(const bf16x8*)(kp + 8);
      const bf16* vp = Vtb + (size_t)(b * 64 + sh) * 2048 + kv * 64 + sc;
      *(bf16x8*)&Vs[sh][sc]     = *(const bf16x8*)vp;
      *(bf16x8*)&Vs[sh][sc + 8] = *(const bf16x8*)(vp + 8);
    }
    __syncthreads();

    f32x4 s[4];
    #pragma unroll
    for (int cf = 0; cf < 4; cf++) {
      bf16x8 kf0 = *(const bf16x8*)&Ks[cf * 16 + r][g * 8];
      bf16x8 kf1 = *(const bf16x8*)&Ks[cf * 16 + r][32 + g * 8];
      f32x4 t = (f32x4){0.f, 0.f, 0.f, 0.f};
      t = MFMA_16x16x32(qf0, kf0, t);
      t = MFMA_16x16x32(qf1, kf1, t);
      s[cf] = t;
    }

    const bool diag = (kv == qt);
    float pm[4] = {-1e30f, -1e30f, -1e30f, -1e30f};
    #pragma unroll
    for (int cf = 0; cf < 4; cf++) {
      #pragma unroll
      for (int j = 0; j < 4; j++) {
        float v = s[cf][j] * scale;
        if (diag && (cf * 16 + r) > (w * 16 + g * 4 + j)) v = -1e30f;
        s[cf][j] = v;
        pm[j] = fmaxf(pm[j], v);
      }
    }
    #pragma unroll
    for (int j = 0; j < 4; j++) {
      #pragma unroll
      for (int msk = 1; msk < 16; msk <<= 1)
        pm[j] = fmaxf(pm[j], __shfl_xor(pm[j], msk, 64));
    }
    float corr[4];
    #pragma unroll
    for (int j = 0; j < 4; j++) {
      float mn = fmaxf(m_r[j], pm[j]);
      corr[j] = __expf(m_r[j] - mn);
      m_r[j] = mn;
    }
    float rs[4] = {0.f, 0.f, 0.f, 0.f};
    #pragma unroll
    for (int cf = 0; cf < 4; cf++) {
      #pragma unroll
      for (int j = 0; j < 4; j++) {
        float pv = __expf(s[cf][j] - m_r[j]);
        s[cf][j] = pv;
        rs[j] += pv;
      }
    }
    #pragma unroll
    for (int j = 0; j < 4; j++) {
      #pragma unroll
      for (int msk = 1; msk < 16; msk <<= 1)
        rs[j] += __shfl_xor(rs[j], msk, 64);
      l_r[j] = l_r[j] * corr[j] + rs[j];
    }
    #pragma unroll
    for (int hf = 0; hf < 4; hf++)
      #pragma unroll
      for (int j = 0; j < 4; j++)
        acc_o[hf][j] *= corr[j];

    #pragma unroll
    for (int cf = 0; cf < 4; cf++)
      #pragma unroll
      for (int j = 0; j < 4; j++)
        Ps[w][g * 4 + j][cf * 16 + r] = (bf16)s[cf][j];

    __syncthreads();

    #pragma unroll
    for (int ss = 0; ss < 2; ss++) {
      bf16x8 pf = *(const bf16x8*)&Ps[w][r][ss * 32 + g * 8];
      #pragma unroll
      for (int hf = 0; hf < 4; hf++) {
        bf16x8 vf = *(const bf16x8*)&Vs[hf * 16 + r][ss * 32 + g * 8];
        acc_o[hf] = MFMA_16x16x32(pf, vf, acc_o[hf]);
      }
    }
    __syncthreads();
  }

  float inv[4];
  #pragma unroll
  for (int j = 0; j < 4; j++) inv[j] = 1.0f / l_r[j];
  const size_t ob = (size_t)(b * 2048 + q0) * 64;
  #pragma unroll
  for (int hf = 0; hf < 4; hf++)
    #pragma unroll
    for (int j = 0; j < 4; j++)
      out[ob + (size_t)(g * 4 + j) * 64 + hf * 16 + r] = acc_o[hf][j] * inv[j];
}

// ---------------------------------------------------------------------------
extern "C" void kernel_launch(void* const* d_in, const int* in_sizes, int n_in,
                              void* d_out, int out_size, void* d_ws, size_t ws_size,
                              hipStream_t stream)
{
  const float* q  = (const float*)d_in[0];
  const float* k  = (const float*)d_in[1];
  const float* Wq = (const float*)d_in[2];
  const float* Wk = (const float*)d_in[3];
  const float* Wv = (const float*)d_in[4];
  float* out = (float*)d_out;

  char* ws = (char*)d_ws;
  bf16* Qb  = (bf16*)(ws);                      // [16*2048][64] bf16, 4MB
  bf16* Kb  = (bf16*)(ws + (4u << 20));         // [16*2048][64] bf16, 4MB
  bf16* Vtb = (bf16*)(ws + (8u << 20));         // [16][64][2048] bf16, 4MB
  bf16* Wt  = (bf16*)(ws + (12u << 20));        // [3][64][1024] bf16, 384KB

  hipLaunchKernelGGL(wtrans_kernel, dim3(768), dim3(256), 0, stream,
                     Wq, Wk, Wv, Wt);
  hipLaunchKernelGGL(proj_kernel, dim3(256), dim3(512),
                     (64 * 1024 * 2) + (8 * 512 * 4) /* 144 KB dynamic LDS */,
                     stream, q, k, Wt, Qb, Kb, Vtb);
  hipLaunchKernelGGL(attn_kernel, dim3(32, 16), dim3(256), 0, stream,
                     Qb, Kb, Vtb, out);
}